// Round 18
// baseline (587.504 us; speedup 1.0000x reference)
//
#include <hip/hip_runtime.h>
#include <hip/hip_bf16.h>
#include <stdint.h>

// BitNet MNIST MLP, Round 18: GEMM plateau diagnosed as LDS-read-ISSUE bound
// (2 blk x 8 waves x 28 ds_read x 12cyc = 5376 cyc/K-tile = observed 5600).
// Fix: B operand read DIRECTLY global->reg (w1q/w2q are L2-resident; same
// values as the staged path). ds_reads 28->16/wave/K-tile, LDS 128->64 KB
// (A only). r11 phase skeleton/read placements/slot lifetimes unchanged.
// Fence: A-stages are the only outstanding VMEM at P4 -> vmcnt(4).

typedef __attribute__((ext_vector_type(8))) short short8;
typedef __attribute__((ext_vector_type(4))) float f32x4;

#define B_TOTAL 65536
#define IN_DIM 784
#define IN_PAD 832
#define H_DIM 1024
#define OUT_DIM 10
#define OUT_PAD 16

__device__ __forceinline__ unsigned short f2bf(float f) {
    union { float f; unsigned u; } c; c.f = f;
    unsigned r = c.u + 0x7FFFu + ((c.u >> 16) & 1u);
    return (unsigned short)(r >> 16);
}
__device__ __forceinline__ float bf2f(unsigned short h) {
    union { unsigned u; float f; } c; c.u = ((unsigned)h) << 16;
    return c.f;
}

// exact-gelu via A&S 7.1.26 erf approximation, |eps| <= 1.5e-7.
__device__ __forceinline__ float gelu_fast(float t) {
    const float z = t * 0.70710678118f;
    const float s = fabsf(z);
    const float tt = 1.0f / (1.0f + 0.3275911f * s);
    const float e = __expf(-s * s);
    float p = fmaf(tt, 1.061405429f, -1.453152027f);
    p = fmaf(tt, p, 1.421413741f);
    p = fmaf(tt, p, -0.284496736f);
    p = fmaf(tt, p, 0.254829592f);
    float erfa = fmaf(-p * tt, e, 1.0f);          // erf(|z|)
    erfa = copysignf(erfa, z);
    return 0.5f * t * (1.0f + erfa);
}

#define GLOAD16(gp, lp)                                                        \
    __builtin_amdgcn_global_load_lds(                                          \
        (const __attribute__((address_space(1))) void*)(gp),                   \
        (__attribute__((address_space(3))) void*)(lp), 16, 0, 0)

// ---------- |w| sums for all 3 weights (grid.y selects; double atomics) ----------
__global__ void absum3_kernel(const float* __restrict__ w1, const float* __restrict__ w2,
                              const float* __restrict__ w3, double* acc) {
    __shared__ float red[4];
    const int which = blockIdx.y;
    const float* w = (which == 0) ? w1 : (which == 1) ? w2 : w3;
    const int n = (which == 0) ? H_DIM * IN_DIM : (which == 1) ? H_DIM * H_DIM : OUT_DIM * H_DIM;
    float s = 0.f;
    for (int i = blockIdx.x * blockDim.x + threadIdx.x; i < n; i += gridDim.x * blockDim.x)
        s += fabsf(w[i]);
#pragma unroll
    for (int o = 32; o > 0; o >>= 1) s += __shfl_xor(s, o);
    if ((threadIdx.x & 63) == 0) red[threadIdx.x >> 6] = s;
    __syncthreads();
    if (threadIdx.x == 0) {
        float t = red[0] + red[1] + red[2] + red[3];
        atomicAdd(acc + which, (double)t);
    }
}

// ---------- ternary quantize all 3 weights -> bf16 (grid.y = flat row) ----------
__global__ void quant_all(const float* __restrict__ w1, const float* __restrict__ w2,
                          const float* __restrict__ w3,
                          unsigned short* __restrict__ w1q, unsigned short* __restrict__ w2q,
                          unsigned short* __restrict__ w3q, const double* sums) {
    const int k = blockIdx.x * blockDim.x + threadIdx.x;
    const int y = blockIdx.y;
    const float* w; unsigned short* wq; int o, O, K, Kp, n; const double* sum;
    if (y < 1024)      { w = w1; wq = w1q; o = y;        O = H_DIM;  K = IN_DIM; Kp = IN_PAD; n = H_DIM * IN_DIM;  sum = sums + 0; }
    else if (y < 2048) { w = w2; wq = w2q; o = y - 1024; O = H_DIM;  K = H_DIM;  Kp = H_DIM;  n = H_DIM * H_DIM;  sum = sums + 1; }
    else               { w = w3; wq = w3q; o = y - 2048; O = OUT_DIM; K = H_DIM; Kp = H_DIM;  n = OUT_DIM * H_DIM; sum = sums + 2; }
    if (k >= Kp) return;
    float scale = fmaxf((float)(*sum / (double)n), 1e-5f);
    float q = 0.f;
    if (o < O && k < K) {
        float r = rintf(w[(size_t)o * K + k] / scale);  // round-half-even == jnp.round
        q = fminf(1.f, fmaxf(-1.f, r));
    }
    wq[(size_t)o * Kp + k] = f2bf(q);
}

// ---------- x fp32 [R x 784] -> bf16 [R x 832] (zero-padded) ----------
__global__ __launch_bounds__(256)
void convert_pad(const float* __restrict__ x, unsigned short* __restrict__ xb) {
    const int g = blockIdx.x * 256 + threadIdx.x;   // one 8-col group per thread
    const int row = g / 104;
    const int c = (g % 104) * 8;
    short8 v = 0;
    if (c < IN_DIM) {
        const float* p = x + (size_t)row * IN_DIM + c;
        float4 f0 = *(const float4*)p;
        float4 f1 = *(const float4*)(p + 4);
        v[0] = (short)f2bf(f0.x); v[1] = (short)f2bf(f0.y);
        v[2] = (short)f2bf(f0.z); v[3] = (short)f2bf(f0.w);
        v[4] = (short)f2bf(f1.x); v[5] = (short)f2bf(f1.y);
        v[6] = (short)f2bf(f1.z); v[7] = (short)f2bf(f1.w);
    }
    *(short8*)(xb + (size_t)row * IN_PAD + c) = v;
}

// ---------- GEMM: C[M x 1024] = A[M x KP] * Bq[1024 x KP]^T ----------
// 256x256 tile, 8 waves (2m x 4n), BK=64, 2 K-tile A-only LDS ring (64 KB),
// st_16x32 swizzle on A. B fragments loaded DIRECTLY global->reg (L2-hot).
// Phases (r11 skeleton): P1 Q(0,0), P2 Q(0,1), P3 Q(1,1), P4 Q(1,0).
// Stages: A-g0(t+2)->cur @P2-end, A-g1(t+2)->cur @P4-end; fence vmcnt(4)
// (only the 4 A-stage ops are outstanding; all B loads consumed earlier).
template<int KP>
__global__ __launch_bounds__(512, 2)
void gemm_bt(const unsigned short* __restrict__ A, const unsigned short* __restrict__ Bq,
             unsigned short* __restrict__ C) {
    constexpr int NT = KP / 64;
    __shared__ __attribute__((aligned(16))) unsigned short LDS[32768];  // 64 KB (A only)
    const int tid = threadIdx.x;
    const int lane = tid & 63;
    const int w = tid >> 6;
    const int wm = w >> 2, wn = w & 3;
    const int lr = lane & 15, gq = lane >> 4;
    const int gsw8 = (gq ^ ((lr >> 3) << 1)) * 8;
    const int lrO = lr * 32;
    const int bid = blockIdx.x;
    const int xcd = bid & 7, slot = bid >> 3;
    const int nblk = slot & 3;
    const int mblk = xcd * (gridDim.x >> 5) + (slot >> 2);
    const int m0 = mblk * 256, n0 = nblk * 256;
    const int rS = lane >> 2;
    const int cS = ((lane & 3) ^ ((lane >> 5) << 1)) * 8;
    const int stA0 = w;          // A-g0 slots (read @P1)
    const int stA1 = 8 + w;      // A-g1 slots (read @P2)
    // B fragment base pointers: col = n0 + wn*64 + i*16 + lr, k-octet gq*8
    const unsigned short* bp[4];
#pragma unroll
    for (int i = 0; i < 4; ++i)
        bp[i] = Bq + (size_t)(n0 + wn * 64 + i * 16 + lr) * KP + gq * 8;

#define STG(tt, areaS, st)                                                     \
    {   const unsigned short* _g = A +                                         \
            (size_t)(m0 + ((st) >> 1) * 16 + rS) * KP + (tt) * 64 + ((st) & 1) * 32 + cS; \
        GLOAD16(_g, &LDS[(areaS) + (st) * 512]);                               \
        GLOAD16(_g + (size_t)128 * KP, &LDS[(areaS) + (st) * 512 + 8192]); }
#define RD_A(mq, mf, kk)                                                       \
    (*(const short8*)&LDS[curA + ((wm * 8 + (mq) * 4 + (mf)) * 2 + (kk)) * 512 + lrO + gsw8])
#define GB(nq, nf, kk, tt)                                                     \
    (*(const short8*)(bp[(nq) * 2 + (nf)] + (tt) * 64 + (kk) * 32))
#define MM(mq, nq, mf, nf, kk)                                                 \
    acc[(mq) * 4 + (mf)][(nq) * 2 + (nf)] =                                    \
        __builtin_amdgcn_mfma_f32_16x16x32_bf16(af[mf][kk], bf[nf][kk],        \
            acc[(mq) * 4 + (mf)][(nq) * 2 + (nf)], 0, 0, 0)

    f32x4 acc[8][4] = {};
    short8 af[4][2], bf[2][2];
    // prologue: A(0) -> buf0, drain; A(1) -> buf1 (in flight); bf(nq0, t=0)
    STG(0, 0, stA0); STG(0, 0, stA1);
    asm volatile("s_waitcnt vmcnt(0)" ::: "memory");   // A(0) landed
    STG(1, 16384, stA0); STG(1, 16384, stA1);
    bf[0][0] = GB(0, 0, 0, 0); bf[1][0] = GB(0, 1, 0, 0);
    bf[0][1] = GB(0, 0, 1, 0); bf[1][1] = GB(0, 1, 1, 0);
#pragma unroll 2
    for (int t = 0; t < NT; ++t) {
        const int curA = (t & 1) * 16384;
        // ===== P1: Q(0,0); af0 reads interleaved; bf <- nq1(t) =====
        __builtin_amdgcn_s_barrier();
        af[0][0] = RD_A(0, 0, 0);
        af[1][0] = RD_A(0, 1, 0);
        __builtin_amdgcn_s_setprio(1);
        MM(0, 0, 0, 0, 0); af[2][0] = RD_A(0, 2, 0);
        MM(0, 0, 0, 1, 0); af[3][0] = RD_A(0, 3, 0);
        MM(0, 0, 1, 0, 0); af[0][1] = RD_A(0, 0, 1);
        MM(0, 0, 1, 1, 0); af[1][1] = RD_A(0, 1, 1);
        MM(0, 0, 2, 0, 0); af[2][1] = RD_A(0, 2, 1);
        MM(0, 0, 2, 1, 0); af[3][1] = RD_A(0, 3, 1);
        MM(0, 0, 3, 0, 0);
        MM(0, 0, 3, 1, 0);
        MM(0, 0, 0, 0, 1); bf[0][0] = GB(1, 0, 0, t);   // bf[.][0] dead for kk1
        MM(0, 0, 0, 1, 1); bf[1][0] = GB(1, 1, 0, t);
        MM(0, 0, 1, 0, 1); MM(0, 0, 1, 1, 1);
        MM(0, 0, 2, 0, 1); MM(0, 0, 2, 1, 1);
        MM(0, 0, 3, 0, 1); MM(0, 0, 3, 1, 1);
        __builtin_amdgcn_s_setprio(0);
        bf[0][1] = GB(1, 0, 1, t); bf[1][1] = GB(1, 1, 1, t);
        // ===== P2: Q(0,1); af1 reads interleaved; stage A-g0(t+2) =====
        __builtin_amdgcn_s_barrier();
        __builtin_amdgcn_s_setprio(1);
        MM(0, 1, 0, 0, 0); MM(0, 1, 0, 1, 0); af[0][0] = RD_A(1, 0, 0);
        MM(0, 1, 1, 0, 0); MM(0, 1, 1, 1, 0); af[1][0] = RD_A(1, 1, 0);
        MM(0, 1, 2, 0, 0); MM(0, 1, 2, 1, 0); af[2][0] = RD_A(1, 2, 0);
        MM(0, 1, 3, 0, 0); MM(0, 1, 3, 1, 0); af[3][0] = RD_A(1, 3, 0);
        MM(0, 1, 0, 0, 1); MM(0, 1, 0, 1, 1); af[0][1] = RD_A(1, 0, 1);
        MM(0, 1, 1, 0, 1); MM(0, 1, 1, 1, 1); af[1][1] = RD_A(1, 1, 1);
        MM(0, 1, 2, 0, 1); MM(0, 1, 2, 1, 1); af[2][1] = RD_A(1, 2, 1);
        MM(0, 1, 3, 0, 1); MM(0, 1, 3, 1, 1); af[3][1] = RD_A(1, 3, 1);
        __builtin_amdgcn_s_setprio(0);
        if (t + 2 < NT) STG(t + 2, curA, stA0);
        // ===== P3: Q(1,1); bf <- nq0(t) again (L2-hot) =====
        __builtin_amdgcn_s_barrier();
        __builtin_amdgcn_s_setprio(1);
        MM(1, 1, 0, 0, 0); MM(1, 1, 0, 1, 0);
        MM(1, 1, 1, 0, 0); MM(1, 1, 1, 1, 0);
        MM(1, 1, 2, 0, 0); MM(1, 1, 2, 1, 0);
        MM(1, 1, 3, 0, 0); MM(1, 1, 3, 1, 0);
        MM(1, 1, 0, 0, 1); bf[0][0] = GB(0, 0, 0, t);
        MM(1, 1, 0, 1, 1); bf[1][0] = GB(0, 1, 0, t);
        MM(1, 1, 1, 0, 1); MM(1, 1, 1, 1, 1);
        MM(1, 1, 2, 0, 1); MM(1, 1, 2, 1, 1);
        MM(1, 1, 3, 0, 1); MM(1, 1, 3, 1, 1);
        __builtin_amdgcn_s_setprio(0);
        bf[0][1] = GB(0, 0, 1, t); bf[1][1] = GB(0, 1, 1, t);
        // ===== P4: Q(1,0); stage A-g1(t+2); fence; bf <- nq0(t+1) =====
        __builtin_amdgcn_s_barrier();
        __builtin_amdgcn_s_setprio(1);
        MM(1, 0, 0, 0, 0); MM(1, 0, 0, 1, 0);
        MM(1, 0, 1, 0, 0); MM(1, 0, 1, 1, 0);
        MM(1, 0, 2, 0, 0); MM(1, 0, 2, 1, 0);
        MM(1, 0, 3, 0, 0); MM(1, 0, 3, 1, 0);
        MM(1, 0, 0, 0, 1); MM(1, 0, 0, 1, 1);
        MM(1, 0, 1, 0, 1); MM(1, 0, 1, 1, 1);
        MM(1, 0, 2, 0, 1); MM(1, 0, 2, 1, 1);
        MM(1, 0, 3, 0, 1); MM(1, 0, 3, 1, 1);
        __builtin_amdgcn_s_setprio(0);
        if (t + 2 < NT) STG(t + 2, curA, stA1);
        if (t + 1 < NT) {   // bf(nq0) for next K-tile (L1/L2-hot re-read pattern)
            bf[0][0] = GB(0, 0, 0, t + 1); bf[1][0] = GB(0, 1, 0, t + 1);
            bf[0][1] = GB(0, 0, 1, t + 1); bf[1][1] = GB(0, 1, 1, t + 1);
        }
        // fence: A(t+1) fully landed; A(t+2)'s 4 ops stay in flight
        if (t < NT - 2) { asm volatile("s_waitcnt vmcnt(4)" ::: "memory"); }
        else            { asm volatile("s_waitcnt vmcnt(0)" ::: "memory"); }
    }
    // epilogue: C/D layout col=lane&15, row=(lane>>4)*4+j (HW-verified)
#pragma unroll
    for (int mf = 0; mf < 8; ++mf) {
        const int grow = m0 + wm * 128 + mf * 16 + (lane >> 4) * 4;
#pragma unroll
        for (int nf = 0; nf < 4; ++nf) {
            const int gcol = n0 + wn * 64 + nf * 16 + lr;
            unsigned short* Cp = C + (size_t)grow * H_DIM + gcol;
#pragma unroll
            for (int j = 0; j < 4; ++j) Cp[(size_t)j * H_DIM] = f2bf(acc[mf][nf][j]);
        }
    }
#undef STG
#undef RD_A
#undef GB
#undef MM
}

// ---------- rmsnorm + gelu (layer 1), one wave per 1024-wide row ----------
__global__ __launch_bounds__(256)
void norm_gelu(const unsigned short* __restrict__ Hp, const float* __restrict__ g,
               unsigned short* __restrict__ U) {
    const int row = blockIdx.x * 4 + (threadIdx.x >> 6);
    const int lane = threadIdx.x & 63;
    const unsigned short* rp = Hp + (size_t)row * H_DIM;
    short8 v0 = *(const short8*)(rp + lane * 8);
    short8 v1 = *(const short8*)(rp + 512 + lane * 8);
    float f[16];
#pragma unroll
    for (int j = 0; j < 8; ++j) {
        f[j] = bf2f((unsigned short)v0[j]);
        f[8 + j] = bf2f((unsigned short)v1[j]);
    }
    float s = 0.f;
#pragma unroll
    for (int j = 0; j < 16; ++j) s += f[j] * f[j];
#pragma unroll
    for (int o = 32; o > 0; o >>= 1) s += __shfl_xor(s, o);
    const float rinv = 1.f / sqrtf(s * (1.f / 1024.f) + 1e-6f);
    float4 ga0 = *(const float4*)(g + lane * 8);
    float4 ga1 = *(const float4*)(g + lane * 8 + 4);
    float4 gb0 = *(const float4*)(g + 512 + lane * 8);
    float4 gb1 = *(const float4*)(g + 512 + lane * 8 + 4);
    float gv[16] = {ga0.x, ga0.y, ga0.z, ga0.w, ga1.x, ga1.y, ga1.z, ga1.w,
                    gb0.x, gb0.y, gb0.z, gb0.w, gb1.x, gb1.y, gb1.z, gb1.w};
    short8 o0, o1;
#pragma unroll
    for (int j = 0; j < 8; ++j) {
        o0[j] = (short)f2bf(gelu_fast(f[j] * rinv * gv[j]));
        o1[j] = (short)f2bf(gelu_fast(f[8 + j] * rinv * gv[8 + j]));
    }
    unsigned short* up = U + (size_t)row * H_DIM;
    *(short8*)(up + lane * 8) = o0;
    *(short8*)(up + 512 + lane * 8) = o1;
}

// ---------- fused: rmsnorm + gelu + final 1024->10 GEMM ----------
__global__ __launch_bounds__(256)
void norm_gelu_out(const unsigned short* __restrict__ Hp, const float* __restrict__ g,
                   const unsigned short* __restrict__ w3q, float* __restrict__ out) {
    __shared__ unsigned short Us[16][1032];
    const int tid = threadIdx.x;
    const int lane = tid & 63, wid = tid >> 6;
    const size_t r0 = (size_t)blockIdx.x * 16;
    float4 ga0 = *(const float4*)(g + lane * 8);
    float4 ga1 = *(const float4*)(g + lane * 8 + 4);
    float4 gb0 = *(const float4*)(g + 512 + lane * 8);
    float4 gb1 = *(const float4*)(g + 512 + lane * 8 + 4);
    float gv[16] = {ga0.x, ga0.y, ga0.z, ga0.w, ga1.x, ga1.y, ga1.z, ga1.w,
                    gb0.x, gb0.y, gb0.z, gb0.w, gb1.x, gb1.y, gb1.z, gb1.w};
#pragma unroll
    for (int rr = 0; rr < 4; ++rr) {
        const int row = wid * 4 + rr;
        const unsigned short* rp = Hp + (r0 + row) * H_DIM;
        short8 v0 = *(const short8*)(rp + lane * 8);
        short8 v1 = *(const short8*)(rp + 512 + lane * 8);
        float f[16];
#pragma unroll
        for (int j = 0; j < 8; ++j) {
            f[j] = bf2f((unsigned short)v0[j]);
            f[8 + j] = bf2f((unsigned short)v1[j]);
        }
        float s = 0.f;
#pragma unroll
        for (int j = 0; j < 16; ++j) s += f[j] * f[j];
#pragma unroll
        for (int o = 32; o > 0; o >>= 1) s += __shfl_xor(s, o);
        const float rinv = 1.f / sqrtf(s * (1.f / 1024.f) + 1e-6f);
        short8 o0, o1;
#pragma unroll
        for (int j = 0; j < 8; ++j) {
            o0[j] = (short)f2bf(gelu_fast(f[j] * rinv * gv[j]));
            o1[j] = (short)f2bf(gelu_fast(f[8 + j] * rinv * gv[8 + j]));
        }
        *(short8*)&Us[row][lane * 8] = o0;
        *(short8*)&Us[row][512 + lane * 8] = o1;
    }
    __syncthreads();
    if (wid == 0) {
        const int lr = lane & 15, lk = (lane >> 4) * 8;
        f32x4 acc = {};
#pragma unroll 4
        for (int ks = 0; ks < 32; ++ks) {
            short8 a = *(const short8*)&Us[lr][ks * 32 + lk];
            short8 b = *(const short8*)(w3q + (size_t)lr * H_DIM + ks * 32 + lk);
            acc = __builtin_amdgcn_mfma_f32_16x16x32_bf16(a, b, acc, 0, 0, 0);
        }
        if (lr < OUT_DIM) {
#pragma unroll
            for (int j = 0; j < 4; ++j)
                out[(r0 + (lane >> 4) * 4 + j) * OUT_DIM + lr] = acc[j];
        }
    }
}

extern "C" void kernel_launch(void* const* d_in, const int* in_sizes, int n_in,
                              void* d_out, int out_size, void* d_ws, size_t ws_size,
                              hipStream_t stream) {
    (void)in_sizes; (void)n_in; (void)out_size;
    const float* x  = (const float*)d_in[0];
    const float* w1 = (const float*)d_in[1];
    const float* g1 = (const float*)d_in[2];
    const float* w2 = (const float*)d_in[3];
    const float* g2 = (const float*)d_in[4];
    const float* w3 = (const float*)d_in[5];
    float* out = (float*)d_out;

    uint8_t* ws = (uint8_t*)d_ws;
    double* sums = (double*)ws;
    size_t off = 256;
    unsigned short* w1q = (unsigned short*)(ws + off); off += (size_t)H_DIM * IN_PAD * 2;
    unsigned short* w2q = (unsigned short*)(ws + off); off += (size_t)H_DIM * H_DIM * 2;
    unsigned short* w3q = (unsigned short*)(ws + off); off += (size_t)OUT_PAD * H_DIM * 2;

    size_t rem = (ws_size > off) ? ws_size - off : 0;
    int R = B_TOTAL;
    while (R > 2048 && (size_t)2 * R * H_DIM * 2 > rem) R >>= 1;
    unsigned short* bufA = (unsigned short*)(ws + off);
    unsigned short* bufB = bufA + (size_t)R * H_DIM;

    hipMemsetAsync(sums, 0, 3 * sizeof(double), stream);
    absum3_kernel<<<dim3(128, 3), 256, 0, stream>>>(w1, w2, w3, sums);
    quant_all<<<dim3(4, 2064), 256, 0, stream>>>(w1, w2, w3, w1q, w2q, w3q, sums);

    const int nchunk = B_TOTAL / R;
    for (int c = 0; c < nchunk; ++c) {
        const float* xc = x + (size_t)c * R * IN_DIM;
        convert_pad<<<R * 104 / 256, 256, 0, stream>>>(xc, bufB);
        gemm_bt<IN_PAD><<<(R / 256) * 4, 512, 0, stream>>>(bufB, w1q, bufA);
        norm_gelu<<<R / 4, 256, 0, stream>>>(bufA, g1, bufB);
        gemm_bt<H_DIM><<<(R / 256) * 4, 512, 0, stream>>>(bufB, w2q, bufA);
        norm_gelu_out<<<R / 16, 256, 0, stream>>>(bufA, g2, w3q,
                                                  out + (size_t)c * R * OUT_DIM);
    }
}

// Round 19
// 437.830 us; speedup vs baseline: 1.3419x; 1.3419x over previous
//
#include <hip/hip_runtime.h>
#include <hip/hip_bf16.h>
#include <stdint.h>

// BitNet MNIST MLP, Round 19: CHAMPION REVERT (r17, 440us measured).
// r18's B-direct-from-L2 regressed (240us/gemm): per-lane B frag read is a
// 16-row gather (16 cache lines/instr) and flat-loads polluted the vmcnt FIFO.
// Champion config: r11 4-phase interleaved gemm_bt (both layers), convert_pad,
// norm_gelu, hybrid norm_gelu_out (4-wave norm + w3-from-L2 MFMA).

typedef __attribute__((ext_vector_type(8))) short short8;
typedef __attribute__((ext_vector_type(4))) float f32x4;

#define B_TOTAL 65536
#define IN_DIM 784
#define IN_PAD 832
#define H_DIM 1024
#define OUT_DIM 10
#define OUT_PAD 16

__device__ __forceinline__ unsigned short f2bf(float f) {
    union { float f; unsigned u; } c; c.f = f;
    unsigned r = c.u + 0x7FFFu + ((c.u >> 16) & 1u);
    return (unsigned short)(r >> 16);
}
__device__ __forceinline__ float bf2f(unsigned short h) {
    union { unsigned u; float f; } c; c.u = ((unsigned)h) << 16;
    return c.f;
}

// exact-gelu via A&S 7.1.26 erf approximation, |eps| <= 1.5e-7.
__device__ __forceinline__ float gelu_fast(float t) {
    const float z = t * 0.70710678118f;
    const float s = fabsf(z);
    const float tt = 1.0f / (1.0f + 0.3275911f * s);
    const float e = __expf(-s * s);
    float p = fmaf(tt, 1.061405429f, -1.453152027f);
    p = fmaf(tt, p, 1.421413741f);
    p = fmaf(tt, p, -0.284496736f);
    p = fmaf(tt, p, 0.254829592f);
    float erfa = fmaf(-p * tt, e, 1.0f);          // erf(|z|)
    erfa = copysignf(erfa, z);
    return 0.5f * t * (1.0f + erfa);
}

#define GLOAD16(gp, lp)                                                        \
    __builtin_amdgcn_global_load_lds(                                          \
        (const __attribute__((address_space(1))) void*)(gp),                   \
        (__attribute__((address_space(3))) void*)(lp), 16, 0, 0)

// ---------- |w| sums for all 3 weights (grid.y selects; double atomics) ----------
__global__ void absum3_kernel(const float* __restrict__ w1, const float* __restrict__ w2,
                              const float* __restrict__ w3, double* acc) {
    __shared__ float red[4];
    const int which = blockIdx.y;
    const float* w = (which == 0) ? w1 : (which == 1) ? w2 : w3;
    const int n = (which == 0) ? H_DIM * IN_DIM : (which == 1) ? H_DIM * H_DIM : OUT_DIM * H_DIM;
    float s = 0.f;
    for (int i = blockIdx.x * blockDim.x + threadIdx.x; i < n; i += gridDim.x * blockDim.x)
        s += fabsf(w[i]);
#pragma unroll
    for (int o = 32; o > 0; o >>= 1) s += __shfl_xor(s, o);
    if ((threadIdx.x & 63) == 0) red[threadIdx.x >> 6] = s;
    __syncthreads();
    if (threadIdx.x == 0) {
        float t = red[0] + red[1] + red[2] + red[3];
        atomicAdd(acc + which, (double)t);
    }
}

// ---------- ternary quantize all 3 weights -> bf16 (grid.y = flat row) ----------
__global__ void quant_all(const float* __restrict__ w1, const float* __restrict__ w2,
                          const float* __restrict__ w3,
                          unsigned short* __restrict__ w1q, unsigned short* __restrict__ w2q,
                          unsigned short* __restrict__ w3q, const double* sums) {
    const int k = blockIdx.x * blockDim.x + threadIdx.x;
    const int y = blockIdx.y;
    const float* w; unsigned short* wq; int o, O, K, Kp, n; const double* sum;
    if (y < 1024)      { w = w1; wq = w1q; o = y;        O = H_DIM;  K = IN_DIM; Kp = IN_PAD; n = H_DIM * IN_DIM;  sum = sums + 0; }
    else if (y < 2048) { w = w2; wq = w2q; o = y - 1024; O = H_DIM;  K = H_DIM;  Kp = H_DIM;  n = H_DIM * H_DIM;  sum = sums + 1; }
    else               { w = w3; wq = w3q; o = y - 2048; O = OUT_DIM; K = H_DIM; Kp = H_DIM;  n = OUT_DIM * H_DIM; sum = sums + 2; }
    if (k >= Kp) return;
    float scale = fmaxf((float)(*sum / (double)n), 1e-5f);
    float q = 0.f;
    if (o < O && k < K) {
        float r = rintf(w[(size_t)o * K + k] / scale);  // round-half-even == jnp.round
        q = fminf(1.f, fmaxf(-1.f, r));
    }
    wq[(size_t)o * Kp + k] = f2bf(q);
}

// ---------- x fp32 [R x 784] -> bf16 [R x 832] (zero-padded) ----------
__global__ __launch_bounds__(256)
void convert_pad(const float* __restrict__ x, unsigned short* __restrict__ xb) {
    const int g = blockIdx.x * 256 + threadIdx.x;   // one 8-col group per thread
    const int row = g / 104;
    const int c = (g % 104) * 8;
    short8 v = 0;
    if (c < IN_DIM) {
        const float* p = x + (size_t)row * IN_DIM + c;
        float4 f0 = *(const float4*)p;
        float4 f1 = *(const float4*)(p + 4);
        v[0] = (short)f2bf(f0.x); v[1] = (short)f2bf(f0.y);
        v[2] = (short)f2bf(f0.z); v[3] = (short)f2bf(f0.w);
        v[4] = (short)f2bf(f1.x); v[5] = (short)f2bf(f1.y);
        v[6] = (short)f2bf(f1.z); v[7] = (short)f2bf(f1.w);
    }
    *(short8*)(xb + (size_t)row * IN_PAD + c) = v;
}

// ---------- GEMM (r11-interleave, verified best): C = A * Bq^T ----------
template<int KP>
__global__ __launch_bounds__(512, 2)
void gemm_bt(const unsigned short* __restrict__ A, const unsigned short* __restrict__ Bq,
             unsigned short* __restrict__ C) {
    constexpr int NT = KP / 64;
    __shared__ __attribute__((aligned(16))) unsigned short LDS[65536];
    const int tid = threadIdx.x;
    const int lane = tid & 63;
    const int w = tid >> 6;
    const int wm = w >> 2, wn = w & 3;
    const int lr = lane & 15, gq = lane >> 4;
    const int gsw8 = (gq ^ ((lr >> 3) << 1)) * 8;
    const int lrO = lr * 32;
    const int bid = blockIdx.x;
    const int xcd = bid & 7, slot = bid >> 3;
    const int nblk = slot & 3;
    const int mblk = xcd * (gridDim.x >> 5) + (slot >> 2);
    const int m0 = mblk * 256, n0 = nblk * 256;
    const int rS = lane >> 2;
    const int cS = ((lane & 3) ^ ((lane >> 5) << 1)) * 8;
    const int stA0 = w;
    const int stA1 = 8 + w;
    const int stB_P1 = (w >> 2) * 8 + (w & 3);
    const int stB_P3 = stB_P1 + 4;

#define STG(gbase, areaS, st)                                                  \
    {   const unsigned short* _g = (gbase) +                                   \
            (size_t)(((st) >> 1) * 16 + rS) * KP + ((st) & 1) * 32 + cS;       \
        GLOAD16(_g, &LDS[(areaS) + (st) * 512]);                               \
        GLOAD16(_g + (size_t)128 * KP, &LDS[(areaS) + (st) * 512 + 8192]); }
#define RD_A(mq, mf, kk)                                                       \
    (*(const short8*)&LDS[curS + ((wm * 8 + (mq) * 4 + (mf)) * 2 + (kk)) * 512 + lrO + gsw8])
#define RD_B(nq, nf, kk)                                                       \
    (*(const short8*)&LDS[curS + 16384 + ((wn * 4 + (nq) * 2 + (nf)) * 2 + (kk)) * 512 + lrO + gsw8])
#define MM(mq, nq, mf, nf, kk)                                                 \
    acc[(mq) * 4 + (mf)][(nq) * 2 + (nf)] =                                    \
        __builtin_amdgcn_mfma_f32_16x16x32_bf16(af[mf][kk], bf[nf][kk],        \
            acc[(mq) * 4 + (mf)][(nq) * 2 + (nf)], 0, 0, 0)

    f32x4 acc[8][4] = {};
    short8 af[4][2], bf[2][2];
    STG(A + (size_t)m0 * KP, 0, stA0);
    STG(Bq + (size_t)n0 * KP, 16384, stB_P1);
    STG(Bq + (size_t)n0 * KP, 16384, stB_P3);
    STG(A + (size_t)m0 * KP, 0, stA1);
    STG(A + (size_t)m0 * KP + 64, 32768, stA0);
    STG(Bq + (size_t)n0 * KP + 64, 49152, stB_P3);
    STG(A + (size_t)m0 * KP + 64, 32768, stA1);
    asm volatile("s_waitcnt vmcnt(6)" ::: "memory");
#pragma unroll 2
    for (int t = 0; t < NT; ++t) {
        const int curS = (t & 1) * 32768;
        const int nxtS = curS ^ 32768;
        __builtin_amdgcn_s_barrier();
        af[0][0] = RD_A(0, 0, 0); bf[0][0] = RD_B(0, 0, 0);
        af[1][0] = RD_A(0, 1, 0); bf[1][0] = RD_B(0, 1, 0);
        __builtin_amdgcn_s_setprio(1);
        MM(0, 0, 0, 0, 0); af[2][0] = RD_A(0, 2, 0);
        MM(0, 0, 0, 1, 0); af[3][0] = RD_A(0, 3, 0);
        MM(0, 0, 1, 0, 0); af[0][1] = RD_A(0, 0, 1);
        MM(0, 0, 1, 1, 0); bf[0][1] = RD_B(0, 0, 1);
        MM(0, 0, 2, 0, 0); af[1][1] = RD_A(0, 1, 1);
        MM(0, 0, 2, 1, 0); bf[1][1] = RD_B(0, 1, 1);
        MM(0, 0, 3, 0, 0); af[2][1] = RD_A(0, 2, 1);
        MM(0, 0, 3, 1, 0); af[3][1] = RD_A(0, 3, 1);
        MM(0, 0, 0, 0, 1); bf[0][0] = RD_B(1, 0, 0);
        MM(0, 0, 0, 1, 1); bf[1][0] = RD_B(1, 1, 0);
        MM(0, 0, 1, 0, 1); MM(0, 0, 1, 1, 1);
        MM(0, 0, 2, 0, 1); MM(0, 0, 2, 1, 1);
        MM(0, 0, 3, 0, 1); MM(0, 0, 3, 1, 1);
        __builtin_amdgcn_s_setprio(0);
        bf[0][1] = RD_B(1, 0, 1); bf[1][1] = RD_B(1, 1, 1);
        if (t + 1 < NT) STG(Bq + (size_t)n0 * KP + (t + 1) * 64, nxtS + 16384, stB_P1);
        __builtin_amdgcn_s_barrier();
        __builtin_amdgcn_s_setprio(1);
        MM(0, 1, 0, 0, 0); MM(0, 1, 0, 1, 0); af[0][0] = RD_A(1, 0, 0);
        MM(0, 1, 1, 0, 0); MM(0, 1, 1, 1, 0); af[1][0] = RD_A(1, 1, 0);
        MM(0, 1, 2, 0, 0); MM(0, 1, 2, 1, 0); af[2][0] = RD_A(1, 2, 0);
        MM(0, 1, 3, 0, 0); MM(0, 1, 3, 1, 0); af[3][0] = RD_A(1, 3, 0);
        MM(0, 1, 0, 0, 1); MM(0, 1, 0, 1, 1); af[0][1] = RD_A(1, 0, 1);
        MM(0, 1, 1, 0, 1); MM(0, 1, 1, 1, 1); af[1][1] = RD_A(1, 1, 1);
        MM(0, 1, 2, 0, 1); MM(0, 1, 2, 1, 1); af[2][1] = RD_A(1, 2, 1);
        MM(0, 1, 3, 0, 1); MM(0, 1, 3, 1, 1); af[3][1] = RD_A(1, 3, 1);
        __builtin_amdgcn_s_setprio(0);
        if (t + 2 < NT) STG(A + (size_t)m0 * KP + (t + 2) * 64, curS, stA0);
        __builtin_amdgcn_s_barrier();
        __builtin_amdgcn_s_setprio(1);
        MM(1, 1, 0, 0, 0); MM(1, 1, 0, 1, 0);
        MM(1, 1, 1, 0, 0); MM(1, 1, 1, 1, 0);
        MM(1, 1, 2, 0, 0); MM(1, 1, 2, 1, 0);
        MM(1, 1, 3, 0, 0); MM(1, 1, 3, 1, 0);
        MM(1, 1, 0, 0, 1); bf[0][0] = RD_B(0, 0, 0);
        MM(1, 1, 0, 1, 1); bf[1][0] = RD_B(0, 1, 0);
        MM(1, 1, 1, 0, 1); MM(1, 1, 1, 1, 1);
        MM(1, 1, 2, 0, 1); MM(1, 1, 2, 1, 1);
        MM(1, 1, 3, 0, 1); MM(1, 1, 3, 1, 1);
        __builtin_amdgcn_s_setprio(0);
        bf[0][1] = RD_B(0, 0, 1); bf[1][1] = RD_B(0, 1, 1);
        if (t + 2 < NT) STG(Bq + (size_t)n0 * KP + (t + 2) * 64, curS + 16384, stB_P3);
        __builtin_amdgcn_s_barrier();
        __builtin_amdgcn_s_setprio(1);
        MM(1, 0, 0, 0, 0); MM(1, 0, 0, 1, 0);
        MM(1, 0, 1, 0, 0); MM(1, 0, 1, 1, 0);
        MM(1, 0, 2, 0, 0); MM(1, 0, 2, 1, 0);
        MM(1, 0, 3, 0, 0); MM(1, 0, 3, 1, 0);
        MM(1, 0, 0, 0, 1); MM(1, 0, 0, 1, 1);
        MM(1, 0, 1, 0, 1); MM(1, 0, 1, 1, 1);
        MM(1, 0, 2, 0, 1); MM(1, 0, 2, 1, 1);
        MM(1, 0, 3, 0, 1); MM(1, 0, 3, 1, 1);
        __builtin_amdgcn_s_setprio(0);
        if (t + 2 < NT) STG(A + (size_t)m0 * KP + (t + 2) * 64, curS, stA1);
        if (t < NT - 2) { asm volatile("s_waitcnt vmcnt(6)" ::: "memory"); }
        else            { asm volatile("s_waitcnt vmcnt(0)" ::: "memory"); }
    }
#pragma unroll
    for (int mf = 0; mf < 8; ++mf) {
        const int grow = m0 + wm * 128 + mf * 16 + (lane >> 4) * 4;
#pragma unroll
        for (int nf = 0; nf < 4; ++nf) {
            const int gcol = n0 + wn * 64 + nf * 16 + lr;
            unsigned short* Cp = C + (size_t)grow * H_DIM + gcol;
#pragma unroll
            for (int j = 0; j < 4; ++j) Cp[(size_t)j * H_DIM] = f2bf(acc[mf][nf][j]);
        }
    }
#undef STG
#undef RD_A
#undef RD_B
#undef MM
}

// ---------- rmsnorm + gelu (layer 1), one wave per 1024-wide row ----------
__global__ __launch_bounds__(256)
void norm_gelu(const unsigned short* __restrict__ Hp, const float* __restrict__ g,
               unsigned short* __restrict__ U) {
    const int row = blockIdx.x * 4 + (threadIdx.x >> 6);
    const int lane = threadIdx.x & 63;
    const unsigned short* rp = Hp + (size_t)row * H_DIM;
    short8 v0 = *(const short8*)(rp + lane * 8);
    short8 v1 = *(const short8*)(rp + 512 + lane * 8);
    float f[16];
#pragma unroll
    for (int j = 0; j < 8; ++j) {
        f[j] = bf2f((unsigned short)v0[j]);
        f[8 + j] = bf2f((unsigned short)v1[j]);
    }
    float s = 0.f;
#pragma unroll
    for (int j = 0; j < 16; ++j) s += f[j] * f[j];
#pragma unroll
    for (int o = 32; o > 0; o >>= 1) s += __shfl_xor(s, o);
    const float rinv = 1.f / sqrtf(s * (1.f / 1024.f) + 1e-6f);
    float4 ga0 = *(const float4*)(g + lane * 8);
    float4 ga1 = *(const float4*)(g + lane * 8 + 4);
    float4 gb0 = *(const float4*)(g + 512 + lane * 8);
    float4 gb1 = *(const float4*)(g + 512 + lane * 8 + 4);
    float gv[16] = {ga0.x, ga0.y, ga0.z, ga0.w, ga1.x, ga1.y, ga1.z, ga1.w,
                    gb0.x, gb0.y, gb0.z, gb0.w, gb1.x, gb1.y, gb1.z, gb1.w};
    short8 o0, o1;
#pragma unroll
    for (int j = 0; j < 8; ++j) {
        o0[j] = (short)f2bf(gelu_fast(f[j] * rinv * gv[j]));
        o1[j] = (short)f2bf(gelu_fast(f[8 + j] * rinv * gv[8 + j]));
    }
    unsigned short* up = U + (size_t)row * H_DIM;
    *(short8*)(up + lane * 8) = o0;
    *(short8*)(up + 512 + lane * 8) = o1;
}

// ---------- fused: rmsnorm + gelu + final 1024->10 GEMM ----------
// 256 threads: 4 waves norm+gelu 4 rows each -> Us (33 KB, 4 blocks/CU,
// 16 waves/CU); wave 0 then runs 32 MFMAs with w3 B-frags direct from L2.
__global__ __launch_bounds__(256)
void norm_gelu_out(const unsigned short* __restrict__ Hp, const float* __restrict__ g,
                   const unsigned short* __restrict__ w3q, float* __restrict__ out) {
    __shared__ unsigned short Us[16][1032];
    const int tid = threadIdx.x;
    const int lane = tid & 63, wid = tid >> 6;
    const size_t r0 = (size_t)blockIdx.x * 16;
    float4 ga0 = *(const float4*)(g + lane * 8);
    float4 ga1 = *(const float4*)(g + lane * 8 + 4);
    float4 gb0 = *(const float4*)(g + 512 + lane * 8);
    float4 gb1 = *(const float4*)(g + 512 + lane * 8 + 4);
    float gv[16] = {ga0.x, ga0.y, ga0.z, ga0.w, ga1.x, ga1.y, ga1.z, ga1.w,
                    gb0.x, gb0.y, gb0.z, gb0.w, gb1.x, gb1.y, gb1.z, gb1.w};
#pragma unroll
    for (int rr = 0; rr < 4; ++rr) {
        const int row = wid * 4 + rr;
        const unsigned short* rp = Hp + (r0 + row) * H_DIM;
        short8 v0 = *(const short8*)(rp + lane * 8);
        short8 v1 = *(const short8*)(rp + 512 + lane * 8);
        float f[16];
#pragma unroll
        for (int j = 0; j < 8; ++j) {
            f[j] = bf2f((unsigned short)v0[j]);
            f[8 + j] = bf2f((unsigned short)v1[j]);
        }
        float s = 0.f;
#pragma unroll
        for (int j = 0; j < 16; ++j) s += f[j] * f[j];
#pragma unroll
        for (int o = 32; o > 0; o >>= 1) s += __shfl_xor(s, o);
        const float rinv = 1.f / sqrtf(s * (1.f / 1024.f) + 1e-6f);
        short8 o0, o1;
#pragma unroll
        for (int j = 0; j < 8; ++j) {
            o0[j] = (short)f2bf(gelu_fast(f[j] * rinv * gv[j]));
            o1[j] = (short)f2bf(gelu_fast(f[8 + j] * rinv * gv[8 + j]));
        }
        *(short8*)&Us[row][lane * 8] = o0;
        *(short8*)&Us[row][512 + lane * 8] = o1;
    }
    __syncthreads();
    if (wid == 0) {
        const int lr = lane & 15, lk = (lane >> 4) * 8;
        f32x4 acc = {};
#pragma unroll 4
        for (int ks = 0; ks < 32; ++ks) {
            short8 a = *(const short8*)&Us[lr][ks * 32 + lk];
            short8 b = *(const short8*)(w3q + (size_t)lr * H_DIM + ks * 32 + lk);
            acc = __builtin_amdgcn_mfma_f32_16x16x32_bf16(a, b, acc, 0, 0, 0);
        }
        // C/D: col=lane&15 (= output o), row=(lane>>4)*4+j (= batch row)
        if (lr < OUT_DIM) {
#pragma unroll
            for (int j = 0; j < 4; ++j)
                out[(r0 + (lane >> 4) * 4 + j) * OUT_DIM + lr] = acc[j];
        }
    }
}

extern "C" void kernel_launch(void* const* d_in, const int* in_sizes, int n_in,
                              void* d_out, int out_size, void* d_ws, size_t ws_size,
                              hipStream_t stream) {
    (void)in_sizes; (void)n_in; (void)out_size;
    const float* x  = (const float*)d_in[0];
    const float* w1 = (const float*)d_in[1];
    const float* g1 = (const float*)d_in[2];
    const float* w2 = (const float*)d_in[3];
    const float* g2 = (const float*)d_in[4];
    const float* w3 = (const float*)d_in[5];
    float* out = (float*)d_out;

    uint8_t* ws = (uint8_t*)d_ws;
    double* sums = (double*)ws;
    size_t off = 256;
    unsigned short* w1q = (unsigned short*)(ws + off); off += (size_t)H_DIM * IN_PAD * 2;
    unsigned short* w2q = (unsigned short*)(ws + off); off += (size_t)H_DIM * H_DIM * 2;
    unsigned short* w3q = (unsigned short*)(ws + off); off += (size_t)OUT_PAD * H_DIM * 2;

    size_t rem = (ws_size > off) ? ws_size - off : 0;
    int R = B_TOTAL;
    while (R > 2048 && (size_t)2 * R * H_DIM * 2 > rem) R >>= 1;
    unsigned short* bufA = (unsigned short*)(ws + off);
    unsigned short* bufB = bufA + (size_t)R * H_DIM;

    hipMemsetAsync(sums, 0, 3 * sizeof(double), stream);
    absum3_kernel<<<dim3(128, 3), 256, 0, stream>>>(w1, w2, w3, sums);
    quant_all<<<dim3(4, 2064), 256, 0, stream>>>(w1, w2, w3, w1q, w2q, w3q, sums);

    const int nchunk = B_TOTAL / R;
    for (int c = 0; c < nchunk; ++c) {
        const float* xc = x + (size_t)c * R * IN_DIM;
        convert_pad<<<R * 104 / 256, 256, 0, stream>>>(xc, bufB);
        gemm_bt<IN_PAD><<<(R / 256) * 4, 512, 0, stream>>>(bufB, w1q, bufA);
        norm_gelu<<<R / 4, 256, 0, stream>>>(bufA, g1, bufB);
        gemm_bt<H_DIM><<<(R / 256) * 4, 512, 0, stream>>>(bufB, w2q, bufA);
        norm_gelu_out<<<R / 16, 256, 0, stream>>>(bufA, g2, w3q,
                                                  out + (size_t)c * R * OUT_DIM);
    }
}